// Round 3
// baseline (888.848 us; speedup 1.0000x reference)
//
#include <hip/hip_runtime.h>

// VQ nearest-codebook: N=262144 rows x D=64, K=1024 codes.
// Numerics contract (bit-exact vs np f32 reference, verified round 2):
//   dist_k = fl32( fl32(zsq - 2*dot_k) + cbsq_k ), argmin -> lowest index wins.
//   dot_k MUST be one sequential fmaf chain d=0..63 (OpenBLAS order). DO NOT
//   re-associate. zsq/cbsq: f64-accumulate then round (tie-invariant).
//
// Perf notes:
//   __launch_bounds__(256, 4): VGPR cap 128 -- without the min-waves hint the
//   backend spilled z[64] to scratch (R2: VGPR=40, +67MB scratch writes,
//   850us). z must stay in VGPRs; 4 waves/SIMD hide codebook s_load latency.
//   #pragma unroll 1 on the k-loop: keep one codebook row (64 SGPRs) live,
//   don't let unrolling double SGPR pressure into spills.

#define VQ_D 64
#define VQ_MAXK 1024

__global__ __launch_bounds__(256, 4) void vq_argmin_kernel(
    const float* __restrict__ z_e,
    const float* __restrict__ cb,
    float* __restrict__ out,   // [N*D] z_q, then [N] indices (as float)
    int N, int K)
{
    __shared__ float s_cbsq[VQ_MAXK];

    // cb_sq per code: f64 accumulate, round once to f32.
    for (int k = threadIdx.x; k < K; k += blockDim.x) {
        const float* c = cb + (size_t)k * VQ_D;
        double s = 0.0;
        #pragma unroll
        for (int d = 0; d < VQ_D; ++d) { double v = (double)c[d]; s += v * v; }
        s_cbsq[k] = (float)s;
    }
    __syncthreads();

    const int n = blockIdx.x * blockDim.x + threadIdx.x;
    if (n >= N) return;

    // z row into registers (16 x float4). Must stay in VGPRs (see header).
    float z[VQ_D];
    const float4* zp = (const float4*)(z_e + (size_t)n * VQ_D);
    #pragma unroll
    for (int i = 0; i < VQ_D / 4; ++i) {
        float4 v = zp[i];
        z[4*i+0] = v.x; z[4*i+1] = v.y; z[4*i+2] = v.z; z[4*i+3] = v.w;
    }

    // ||z||^2: f64 accumulate, round once (whole-ulp shifts can't flip ties).
    double zsqd = 0.0;
    #pragma unroll
    for (int d = 0; d < VQ_D; ++d) zsqd += (double)z[d] * (double)z[d];
    const float zsq = (float)zsqd;

    float best = 3.4e38f;
    int bestk = 0;

    #pragma unroll 1
    for (int k = 0; k < K; ++k) {
        const float* __restrict__ c = cb + (size_t)k * VQ_D;  // wave-uniform -> s_load
        // Sequential fused-FMA chain, ascending d. DO NOT reorder.
        float s = 0.f;
        #pragma unroll
        for (int d = 0; d < VQ_D; ++d) s = fmaf(z[d], c[d], s);
        const float u    = zsq - 2.0f * s;     // fp32 round, as reference
        const float dist = u + s_cbsq[k];      // fp32 round, as reference
        if (dist < best) { best = dist; bestk = k; }  // strict <: lowest index wins
    }

    // z_q gather (codebook is L2/L3-resident).
    const float4* cq = (const float4*)(cb + (size_t)bestk * VQ_D);
    float4* oq = (float4*)(out + (size_t)n * VQ_D);
    #pragma unroll
    for (int i = 0; i < VQ_D / 4; ++i) oq[i] = cq[i];

    // Index as float (exact for k < 2^24).
    out[(size_t)N * VQ_D + n] = (float)bestk;
}

extern "C" void kernel_launch(void* const* d_in, const int* in_sizes, int n_in,
                              void* d_out, int out_size, void* d_ws, size_t ws_size,
                              hipStream_t stream) {
    const float* z_e = (const float*)d_in[0];
    const float* cb  = (const float*)d_in[1];
    float* out = (float*)d_out;

    const int N = in_sizes[0] / VQ_D;
    const int K = in_sizes[1] / VQ_D;

    const int block = 256;
    const int grid = (N + block - 1) / block;
    vq_argmin_kernel<<<grid, block, 0, stream>>>(z_e, cb, out, N, K);
}

// Round 4
// 760.529 us; speedup vs baseline: 1.1687x; 1.1687x over previous
//
#include <hip/hip_runtime.h>

// VQ nearest-codebook: N=262144 rows x D=64, K=1024 codes.
// Numerics contract (bit-exact vs np f32 reference, verified round 2):
//   dist_k = fl32( fl32(zsq - 2*dot_k) + cbsq_k ), argmin -> lowest index wins.
//   dot_k MUST be one sequential fmaf chain d=0..63 (OpenBLAS accumulation
//   order). DO NOT re-associate. zsq/cbsq: f64-accumulate then round once
//   (whole-ulp shifts of zsq cannot flip ties).
//
// Perf notes:
//   NO per-thread arrays. R1-R3 kept `float z[64]` which SROA could not
//   promote (variable index at SROA time, pre-unroll) -> permanent scratch
//   alloca: VGPR=40, +70MB scratch traffic, 850us, launch_bounds-immune.
//   z row lives in 16 named float4s; codebook row in 16 named float4s loaded
//   up-front each iteration (single waitcnt, then 64 FMAs).
//   __launch_bounds__(256,3): 168-VGPR cap covers worst case (c-row in
//   VGPRs ~144); if c scalarizes to SGPR, actual ~90 VGPR -> 5 waves/SIMD.

#define VQ_D 64
#define VQ_MAXK 1024

// Sequential fused-FMA chain step over one float4 (order x,y,z,w = ascending d).
#define VQ_CH(q, c) do { \
    s = fmaf((q).x, (c).x, s); \
    s = fmaf((q).y, (c).y, s); \
    s = fmaf((q).z, (c).z, s); \
    s = fmaf((q).w, (c).w, s); } while (0)

// f64 sum-of-squares over one float4 (order-free: tie-invariant).
#define VQ_SQ(q) do { \
    zsqd += (double)(q).x * (double)(q).x; \
    zsqd += (double)(q).y * (double)(q).y; \
    zsqd += (double)(q).z * (double)(q).z; \
    zsqd += (double)(q).w * (double)(q).w; } while (0)

__global__ __launch_bounds__(256, 3) void vq_argmin_kernel(
    const float* __restrict__ z_e,
    const float* __restrict__ cb,
    float* __restrict__ out,   // [N*D] z_q, then [N] indices (as float)
    int N, int K)
{
    __shared__ float s_cbsq[VQ_MAXK];

    // cb_sq per code: f64 accumulate, round once to f32. (Verified numerics —
    // do not change.)
    for (int k = threadIdx.x; k < K; k += blockDim.x) {
        const float* c = cb + (size_t)k * VQ_D;
        double s = 0.0;
        #pragma unroll
        for (int d = 0; d < VQ_D; ++d) { double v = (double)c[d]; s += v * v; }
        s_cbsq[k] = (float)s;
    }
    __syncthreads();

    const int n = blockIdx.x * blockDim.x + threadIdx.x;
    if (n >= N) return;

    // z row in 16 named float4 registers (NOT an array — see header).
    const float4* zp = (const float4*)(z_e + (size_t)n * VQ_D);
    float4 q0  = zp[0],  q1  = zp[1],  q2  = zp[2],  q3  = zp[3];
    float4 q4  = zp[4],  q5  = zp[5],  q6  = zp[6],  q7  = zp[7];
    float4 q8  = zp[8],  q9  = zp[9],  q10 = zp[10], q11 = zp[11];
    float4 q12 = zp[12], q13 = zp[13], q14 = zp[14], q15 = zp[15];

    // ||z||^2 in f64, rounded once.
    double zsqd = 0.0;
    VQ_SQ(q0);  VQ_SQ(q1);  VQ_SQ(q2);  VQ_SQ(q3);
    VQ_SQ(q4);  VQ_SQ(q5);  VQ_SQ(q6);  VQ_SQ(q7);
    VQ_SQ(q8);  VQ_SQ(q9);  VQ_SQ(q10); VQ_SQ(q11);
    VQ_SQ(q12); VQ_SQ(q13); VQ_SQ(q14); VQ_SQ(q15);
    const float zsq = (float)zsqd;

    float best = 3.4e38f;
    int bestk = 0;

    #pragma unroll 1
    for (int k = 0; k < K; ++k) {
        // Wave-uniform row address; 16 up-front loads (ILP), then the chain.
        const float4* __restrict__ cp = (const float4*)(cb + (size_t)k * VQ_D);
        float4 c0  = cp[0],  c1  = cp[1],  c2  = cp[2],  c3  = cp[3];
        float4 c4  = cp[4],  c5  = cp[5],  c6  = cp[6],  c7  = cp[7];
        float4 c8  = cp[8],  c9  = cp[9],  c10 = cp[10], c11 = cp[11];
        float4 c12 = cp[12], c13 = cp[13], c14 = cp[14], c15 = cp[15];

        // Sequential fused-FMA chain, ascending d. DO NOT reorder.
        float s = 0.f;
        VQ_CH(q0,  c0);  VQ_CH(q1,  c1);  VQ_CH(q2,  c2);  VQ_CH(q3,  c3);
        VQ_CH(q4,  c4);  VQ_CH(q5,  c5);  VQ_CH(q6,  c6);  VQ_CH(q7,  c7);
        VQ_CH(q8,  c8);  VQ_CH(q9,  c9);  VQ_CH(q10, c10); VQ_CH(q11, c11);
        VQ_CH(q12, c12); VQ_CH(q13, c13); VQ_CH(q14, c14); VQ_CH(q15, c15);

        const float u    = zsq - 2.0f * s;   // fp32 round, as reference
        const float dist = u + s_cbsq[k];    // fp32 round, as reference
        if (dist < best) { best = dist; bestk = k; }  // strict <: lowest k wins
    }

    // z_q gather (codebook L2/L3-resident), float4 stores.
    const float4* cq = (const float4*)(cb + (size_t)bestk * VQ_D);
    float4* oq = (float4*)(out + (size_t)n * VQ_D);
    #pragma unroll
    for (int i = 0; i < VQ_D / 4; ++i) oq[i] = cq[i];

    // Index as float (exact for k < 2^24).
    out[(size_t)N * VQ_D + n] = (float)bestk;
}

extern "C" void kernel_launch(void* const* d_in, const int* in_sizes, int n_in,
                              void* d_out, int out_size, void* d_ws, size_t ws_size,
                              hipStream_t stream) {
    const float* z_e = (const float*)d_in[0];
    const float* cb  = (const float*)d_in[1];
    float* out = (float*)d_out;

    const int N = in_sizes[0] / VQ_D;
    const int K = in_sizes[1] / VQ_D;

    const int block = 256;
    const int grid = (N + block - 1) / block;
    vq_argmin_kernel<<<grid, block, 0, stream>>>(z_e, cb, out, N, K);
}